// Round 7
// baseline (66.629 us; speedup 1.0000x reference)
//
#include <hip/hip_runtime.h>
#include <math.h>

#pragma clang fp contract(off)

#define BATCH 8
#define N_PROP 8000
#define N_GT 256
#define N_ALL 8256
#define PRE_NMS 1000
#define DETS 300
#define IMG 800.0f
#define DW_CLIP 4.135166556742356f
#define NWORDS 32   // 1000 bits -> 32 u32 words
#define NBINS 8192
#define BIN_SCALE 8192.0f
#define MASK_BLOCKS 125   // 125*256 == PRE_NMS*NWORDS
#define PREP_BLOCKS 258   // 258*32  == 8256 proposals

// Correctly-rounded f32 exp/log via double — matches the numpy reference
// transcendentals bit-for-bit (absmax 0.0 since R1). Do not touch.
__device__ __forceinline__ float exf(float x) { return (float)exp((double)x); }
__device__ __forceinline__ float lgf(float x) { return (float)log((double)x); }

__device__ __forceinline__ int score_bin(float s) {
  int b = (int)(s * BIN_SCALE);
  return (b < 0) ? 0 : (b > NBINS - 1 ? NBINS - 1 : b);
}

// bx[] LDS slot swizzle. [validated R3: SQ_LDS_BANK_CONFLICT 3.5M -> 221K]
__device__ __forceinline__ int bxp(int j) { return j ^ ((j >> 5) & 7); }

// Named scalars for the serial scan (R5-validated: arrays scratch-demote in
// complex kernels; named scalars stay in VGPRs).
#define REP32(F) F(0) F(1) F(2) F(3) F(4) F(5) F(6) F(7) F(8) F(9) F(10) \
  F(11) F(12) F(13) F(14) F(15) F(16) F(17) F(18) F(19) F(20) F(21) F(22) \
  F(23) F(24) F(25) F(26) F(27) F(28) F(29) F(30) F(31)

// R7 STRUCTURE (3 kernels, 2 gaps):
//  K1 select_rank: scores from logits in-block; hist/threshold/rank
//     (R11-validated); LAZY decode of only the ~1030 candidate boxes.
//  K2 mask||prep: mask blocks (x<125) + prep match/labels/encode blocks
//     (x>=125) share one dispatch — prep outputs are terminal, mask only
//     needs K1's top_b.  No cross-block communication (R2-R5 lesson:
//     per-block device fences cost ~0.1us each serialized -> never again).
//  K3 scan: R6-validated recurrence + wave-uniform empty-window skip.

// K1: fused score + hist + threshold + HISTOGRAM-RANKED scatter + exact
// rank + lazy candidate decode.  [hist/rank machinery validated R11]
__global__ void __launch_bounds__(1024)
select_rank_kernel(const float* __restrict__ prop,
                   const float* __restrict__ gt,
                   const float* __restrict__ logits,
                   const float* __restrict__ breg,
                   float* __restrict__ top_s,
                   float* __restrict__ top_b) {
  const int b = blockIdx.x;
  const int tid = threadIdx.x;
  const int lane = tid & 63, wid = tid >> 6;
  __shared__ __align__(16) float ssc[N_ALL];          // 33.0 KB
  __shared__ unsigned hist[NBINS];                    // 32.0 KB
  __shared__ __align__(16) float sc2[N_ALL];          // 33.0 KB
  __shared__ unsigned short idx2[N_ALL];              // 16.5 KB
  __shared__ __align__(16) float4 gsh[N_GT];          //  4.0 KB
  __shared__ int s_wt[16], s_wx[16];
  __shared__ int s_T, s_Nc;

  // stage gt boxes (for decode of indices >= N_PROP)
  if (tid < N_GT) gsh[tid] = ((const float4*)(gt + (size_t)b * N_GT * 4))[tid];

  // compute thresholded scores from logits (identical expressions to the
  // old prep epilogue -> bit-exact)
  for (int k = tid; k < N_ALL; k += 1024) {
    const float2 lg = *(const float2*)(logits + ((size_t)b * N_ALL + k) * 2);
    const float m = fmaxf(lg.x, lg.y);
    const float e0 = exf(lg.x - m), e1 = exf(lg.y - m);
    const float s = e1 / (e0 + e1);
    ssc[k] = (s > 0.05f) ? s : -1.0f;
  }
  #pragma unroll
  for (int i = 0; i < NBINS / 1024; ++i) hist[tid + i * 1024] = 0u;
  __syncthreads();
  for (int k = tid; k < N_ALL; k += 1024)
    atomicAdd(&hist[score_bin(ssc[k])], 1u);
  __syncthreads();

  // thread tid owns bins [tid*8, tid*8+8)
  int local = 0;
  #pragma unroll
  for (int i = 0; i < NBINS / 1024; ++i) local += (int)hist[tid * (NBINS / 1024) + i];

  int incl = local;                       // suffix-inclusive within wave
  #pragma unroll
  for (int off = 1; off < 64; off <<= 1) {
    const int u = __shfl_down(incl, off);
    incl += (lane + off < 64) ? u : 0;
  }
  if (lane == 0) s_wt[wid] = incl;
  __syncthreads();
  if (tid < 16) {                         // suffix across the 16 waves
    const int v = s_wt[tid];
    int inc2 = v;
    #pragma unroll
    for (int off = 1; off < 16; off <<= 1) {
      const int u = __shfl_down(inc2, off);
      inc2 += (tid + off < 16) ? u : 0;
    }
    s_wx[tid] = inc2 - v;
  }
  __syncthreads();
  const int sa = (incl - local) + s_wx[wid];  // count in bins above my block

  // descending in-place walk: hist[bin] := count strictly above bin;
  // detect threshold crossing (unique thread) on the way.
  {
    int above = sa;
    const int hi = tid * (NBINS / 1024) + (NBINS / 1024) - 1;
    #pragma unroll
    for (int i = 0; i < NBINS / 1024; ++i) {
      const int bin = hi - i;
      const int c = (int)hist[bin];
      if (above < PRE_NMS && above + c >= PRE_NMS) { s_T = bin; s_Nc = above + c; }
      hist[bin] = (unsigned)above;
      above += c;
    }
  }
  __syncthreads();
  const int T = s_T;
  const int Nc = s_Nc;                    // >= PRE_NMS always (total = 8256)

  // scatter: slot = rank_base(bin) + arbitrary intra-bin offset
  for (int k = tid; k < N_ALL; k += 1024) {
    const float v = ssc[k];
    const int bb = score_bin(v);
    if (bb >= T) {
      const int slot = (int)atomicAdd(&hist[bb], 1u);
      sc2[slot] = v;
      idx2[slot] = (unsigned short)k;
    }
  }
  __syncthreads();

  // resolve exact rank per slot; lazily decode the winning boxes
  // (decode expressions copied verbatim from validated prep epilogue)
  float* tsb = top_s + (size_t)b * PRE_NMS;
  float4* tbb = (float4*)top_b + (size_t)b * PRE_NMS;
  for (int s = tid; s < Nc; s += 1024) {
    const float my = sc2[s];
    const int myb = score_bin(my);
    const int myi = (int)idx2[s];
    int gl = s;
    while (gl > 0 && score_bin(sc2[gl - 1]) == myb) --gl;
    int rank = gl;
    for (int k2 = gl; k2 < Nc; ++k2) {
      const float v = sc2[k2];
      if (score_bin(v) != myb) break;
      if (k2 == s) continue;
      rank += (int)((v > my) | ((v == my) & ((int)idx2[k2] < myi)));
    }
    if (rank < PRE_NMS) {
      tsb[rank] = my;
      float4 pb;
      if (myi < N_PROP) pb = ((const float4*)(prop + (size_t)b * N_PROP * 4))[myi];
      else              pb = gsh[myi - N_PROP];
      const float pw = pb.z - pb.x, ph = pb.w - pb.y;
      const float pcx = pb.x + 0.5f * pw, pcy = pb.y + 0.5f * ph;
      const float4 r = *(const float4*)(breg + (((size_t)b * N_ALL + myi) * 8 + 4));
      const float dx = r.x / 10.0f, dy = r.y / 10.0f;
      const float dw = fminf(r.z / 5.0f, DW_CLIP);
      const float dh = fminf(r.w / 5.0f, DW_CLIP);
      const float cx = dx * pw + pcx, cy = dy * ph + pcy;
      const float w2 = exf(dw) * pw, h2 = exf(dh) * ph;
      float4 bb;
      bb.x = fminf(fmaxf(cx - 0.5f * w2, 0.0f), IMG);
      bb.y = fminf(fmaxf(cy - 0.5f * h2, 0.0f), IMG);
      bb.z = fminf(fmaxf(cx + 0.5f * w2, 0.0f), IMG);
      bb.w = fminf(fmaxf(cy + 0.5f * h2, 0.0f), IMG);
      tbb[rank] = bb;
    }
  }
}

// K2: mask-build (blocks x<125) || prep match/labels/encode (x>=125).
// Two independent jobs sharing one dispatch; no inter-block communication.
// [mask body validated R2/R3; prep match validated R9]
__global__ void __launch_bounds__(256)
mask_prep_kernel(const float* __restrict__ prop,
                 const float* __restrict__ gt,
                 const float* __restrict__ top_b,
                 unsigned* __restrict__ ws_mask,
                 float* __restrict__ out_labels,
                 float* __restrict__ out_regt) {
  const int b = blockIdx.y;
  const int tid = threadIdx.x;
  __shared__ __align__(16) float4 bx[PRE_NMS];     // mask branch (16 KB)
  __shared__ __align__(16) float4 gsh4[N_GT];      // prep branch (4 KB)
  __shared__ float s_best[32];
  __shared__ int s_bi[32];

  if (blockIdx.x < MASK_BLOCKS) {
    // ---------------- mask branch ----------------
    {
      const float4* gb = (const float4*)top_b + (size_t)b * PRE_NMS;
      float4 v0 = gb[tid], v1 = gb[tid + 256], v2 = gb[tid + 512];
      float4 v3 = make_float4(0.f, 0.f, 0.f, 0.f);
      const bool g3 = (tid + 768) < PRE_NMS;
      if (g3) v3 = gb[tid + 768];
      bx[bxp(tid)] = v0; bx[bxp(tid + 256)] = v1; bx[bxp(tid + 512)] = v2;
      if (g3) bx[bxp(tid + 768)] = v3;
    }
    __syncthreads();
    const int idx = blockIdx.x * 256 + tid;        // < 32000 exactly
    const int i = idx >> 5;
    const int w = idx & 31;
    const float4 bi = bx[bxp(i)];
    const float ai = (bi.z - bi.x) * (bi.w - bi.y);
    unsigned bits = 0u;
    const int j0 = w * 32;
    #pragma unroll 8
    for (int jj = 0; jj < 32; ++jj) {
      const int j = j0 + jj;
      if (j > i && j < PRE_NMS) {
        const float4 bj = bx[bxp(j)];
        const float aj = (bj.z - bj.x) * (bj.w - bj.y);
        const float ww = fmaxf(fminf(bi.z, bj.z) - fmaxf(bi.x, bj.x), 0.0f);
        const float hh = fmaxf(fminf(bi.w, bj.w) - fmaxf(bi.y, bj.y), 0.0f);
        const float inter = ww * hh;
        const float iou = inter / (ai + aj - inter);  // NaN>0.5 false
        if (iou > 0.5f) bits |= (1u << jj);
      }
    }
    ws_mask[((size_t)b * PRE_NMS + i) * NWORDS + w] = bits;
  } else {
    // ---------------- prep branch (match + labels + encode only) -------
    {
      const float4* g4 = (const float4*)(gt + (size_t)b * N_GT * 4);
      gsh4[tid] = g4[tid];   // 256 threads == 256 gt
    }
    __syncthreads();

    const int grp = tid >> 3;              // 32 proposals per block
    const int gl  = tid & 7;
    const int j = (blockIdx.x - MASK_BLOCKS) * 32 + grp;   // [0, 8256)

    float x1, y1, x2, y2;
    if (j < N_PROP) {
      const float4 p = ((const float4*)(prop + (size_t)b * N_PROP * 4))[j];
      x1 = p.x; y1 = p.y; x2 = p.z; y2 = p.w;
    } else {
      const float4 g = gsh4[j - N_PROP];
      x1 = g.x; y1 = g.y; x2 = g.z; y2 = g.w;
    }
    const float areaP = (x2 - x1) * (y2 - y1);

    float best = -1.0f; int bi = gl;
    #pragma unroll 4
    for (int t = 0; t < 32; ++t) {
      const int i = gl + (t << 3);       // in-lane ascending -> '>' keeps first
      const float4 g = gsh4[i];
      const float ga = (g.z - g.x) * (g.w - g.y);
      const float w = fmaxf(fminf(g.z, x2) - fmaxf(g.x, x1), 0.0f);
      const float h = fmaxf(fminf(g.w, y2) - fmaxf(g.y, y1), 0.0f);
      const float inter = w * h;
      const float iou = inter / (ga + areaP - inter);
      if (iou > best) { best = iou; bi = i; }
    }
    #pragma unroll
    for (int m = 1; m < 8; m <<= 1) {    // (max, min-index) == first-max
      const float ov = __shfl_xor(best, m, 64);
      const int   oi = __shfl_xor(bi,  m, 64);
      if (ov > best || (ov == best && oi < bi)) { best = ov; bi = oi; }
    }
    if (gl == 0) { s_best[grp] = best; s_bi[grp] = bi; }
    __syncthreads();

    if (tid < 32) {                      // single wave, 32 active lanes
      const int j2 = (blockIdx.x - MASK_BLOCKS) * 32 + tid;
      const float bst = s_best[tid];
      const int   gi  = s_bi[tid];

      float px1, py1, px2, py2;
      if (j2 < N_PROP) {
        const float4 p = ((const float4*)(prop + (size_t)b * N_PROP * 4))[j2];
        px1 = p.x; py1 = p.y; px2 = p.z; py2 = p.w;
      } else {
        const float4 g = gsh4[j2 - N_PROP];
        px1 = g.x; py1 = g.y; px2 = g.z; py2 = g.w;
      }

      out_labels[(size_t)b * N_ALL + j2] = (bst < 0.5f) ? 0.0f : 1.0f;

      const float pw = px2 - px1, ph = py2 - py1;
      const float pcx = px1 + 0.5f * pw, pcy = py1 + 0.5f * ph;
      const float4 gb = gsh4[gi];
      const float gw = gb.z - gb.x, gh = gb.w - gb.y;
      const float gcx = gb.x + 0.5f * gw, gcy = gb.y + 0.5f * gh;
      float4 rt;
      rt.x = 10.0f * (gcx - pcx) / pw;
      rt.y = 10.0f * (gcy - pcy) / ph;
      rt.z = 5.0f * lgf(gw / pw);
      rt.w = 5.0f * lgf(gh / ph);
      ((float4*)out_regt)[(size_t)b * N_ALL + j2] = rt;
    }
  }
}

// K3: serial scan + det-300 selection.  [recurrence validated R0-R6]
// R7: wave-uniform empty-window skip (sw==0 => all mJ=0, sup|=0 — no-op).
__global__ void __launch_bounds__(256)
scan_kernel(const unsigned* __restrict__ ws_mask,
            const float* __restrict__ top_s,
            const float* __restrict__ top_b,
            float* __restrict__ out_detb,
            float* __restrict__ out_dets) {
  const int b = blockIdx.x;
  const int tid = threadIdx.x;
  __shared__ __align__(16) unsigned smask[PRE_NMS * NWORDS];  // 125 KiB
  __shared__ int s_npos;
  __shared__ unsigned s_flw[NWORDS];
  __shared__ int s_pref[NWORDS + 1];
  const float* ts = top_s + (size_t)b * PRE_NMS;

  if (tid == 0) s_npos = 0;
  // deep-pipelined stage: 8000 uint4, 4 groups x 8 loads-to-regs then store
  {
    const uint4* gm = (const uint4*)(ws_mask + (size_t)b * PRE_NMS * NWORDS);
    uint4* sm4 = (uint4*)smask;
    #pragma unroll
    for (int gs = 0; gs < 4; ++gs) {
      const int k0 = gs * 2048 + tid;
      uint4 t0 = gm[k0],        t1 = gm[k0 + 256],  t2 = gm[k0 + 512];
      uint4 t3 = gm[k0 + 768],  t4 = gm[k0 + 1024], t5 = gm[k0 + 1280];
      uint4 t6 = gm[k0 + 1536];
      uint4 t7 = make_uint4(0u, 0u, 0u, 0u);
      const bool g7 = (k0 + 1792) < (PRE_NMS * NWORDS / 4);   // 8000
      if (g7) t7 = gm[k0 + 1792];
      sm4[k0] = t0;        sm4[k0 + 256] = t1;  sm4[k0 + 512] = t2;
      sm4[k0 + 768] = t3;  sm4[k0 + 1024] = t4; sm4[k0 + 1280] = t5;
      sm4[k0 + 1536] = t6;
      if (g7) sm4[k0 + 1792] = t7;
    }
  }
  int cnt = 0;
  for (int k = tid; k < PRE_NMS; k += 256) cnt += (ts[k] > 0.0f) ? 1 : 0;
  __syncthreads();                     // staging visible + s_npos zeroed
  if (cnt) atomicAdd(&s_npos, cnt);

  unsigned keep = 0u;
  if (tid < 64) {                      // wave 0: serial greedy scan
    const int lane = tid;
    const int lw = lane & 31;          // word index (upper half mirrors)
    keep = (lane < NWORDS) ? ((lane == 31) ? 0xFFu : 0xFFFFFFFFu) : 0u;
#define DECLA(J) unsigned rA##J;
    REP32(DECLA)
#undef DECLA
    for (int win = 0; win < 32; ++win) {
      unsigned sw = (unsigned)__builtin_amdgcn_readlane((int)keep, win);
      if (sw) {                        // wave-uniform skip of dead windows
        const int base = win * 32;
#define LOADA(J) rA##J = smask[(base + J) * NWORDS + lw];
        REP32(LOADA)
#undef LOADA
        unsigned sup = 0u;
#define STEPJ(J) { \
        const unsigned mJ = 0u - ((sw >> J) & 1u); \
        const unsigned rwJ = (unsigned)__builtin_amdgcn_readlane((int)rA##J, win); \
        sw &= ~(rwJ & mJ); \
        sup |= (rA##J & mJ); }
        REP32(STEPJ)
#undef STEPJ
        keep &= ~sup;                  // one update per window
      }
    }
  }
  __syncthreads();
  const int n_pos = s_npos;
  if (tid < NWORDS) {                  // wave 0 still holds keep
    const int lo = tid * 32;
    int np = n_pos - lo;
    np = (np < 0) ? 0 : (np > 32 ? 32 : np);
    const unsigned npm = (np >= 32) ? 0xFFFFFFFFu : ((1u << np) - 1u);
    s_flw[tid] = keep & npm;           // keep already 0 beyond bit 999
  }
  __syncthreads();
  if (tid == 0) {
    int s = 0;
    #pragma unroll
    for (int w = 0; w < NWORDS; ++w) { s_pref[w] = s; s += __popc(s_flw[w]); }
    s_pref[NWORDS] = s;
  }
  __syncthreads();
  const int tot = s_pref[NWORDS];

  for (int k = tid; k < PRE_NMS; k += 256) {
    const unsigned fw = s_flw[k >> 5];
    const int fbit = (int)((fw >> (k & 31)) & 1u);
    const int pos = s_pref[k >> 5] + __popc(fw & ((1u << (k & 31)) - 1u));
    int slot = -1; float sval = 0.0f;
    if (fbit) {
      if (pos < DETS) { slot = pos; sval = ts[k]; }
    } else {
      const int s2 = tot + (k - pos);
      if (s2 < DETS) { slot = s2; sval = -1.0f; }
    }
    if (slot >= 0) {
      out_dets[(size_t)b * DETS + slot] = sval;
      ((float4*)out_detb)[(size_t)b * DETS + slot] =
          ((const float4*)top_b)[(size_t)b * PRE_NMS + k];
    }
  }
}

extern "C" void kernel_launch(void* const* d_in, const int* in_sizes, int n_in,
                              void* d_out, int out_size, void* d_ws, size_t ws_size,
                              hipStream_t stream) {
  const float* prop   = (const float*)d_in[0];
  const float* gt     = (const float*)d_in[1];
  const float* logits = (const float*)d_in[2];
  const float* breg   = (const float*)d_in[3];

  float* out        = (float*)d_out;
  float* out_labels = out;                                   // B*N_ALL
  float* out_regt   = out + (size_t)BATCH * N_ALL;           // B*N_ALL*4
  float* out_detb   = out_regt + (size_t)BATCH * N_ALL * 4;  // B*DETS*4
  float* out_dets   = out_detb + (size_t)BATCH * DETS * 4;   // B*DETS

  float* ws_tops   = (float*)d_ws;                            // B*PRE_NMS
  float* ws_topb   = ws_tops + (size_t)BATCH * PRE_NMS;       // B*PRE_NMS*4
  unsigned* ws_mask = (unsigned*)(ws_topb + (size_t)BATCH * PRE_NMS * 4); // B*1000*32

  hipLaunchKernelGGL(select_rank_kernel, dim3(BATCH), dim3(1024), 0, stream,
                     prop, gt, logits, breg, ws_tops, ws_topb);
  hipLaunchKernelGGL(mask_prep_kernel,
                     dim3(MASK_BLOCKS + PREP_BLOCKS, BATCH), dim3(256), 0, stream,
                     prop, gt, ws_topb, ws_mask, out_labels, out_regt);
  hipLaunchKernelGGL(scan_kernel, dim3(BATCH), dim3(256), 0, stream,
                     ws_mask, ws_tops, ws_topb, out_detb, out_dets);
}

// Round 8
// 58.147 us; speedup vs baseline: 1.1459x; 1.1459x over previous
//
#include <hip/hip_runtime.h>
#include <math.h>

#pragma clang fp contract(off)

#define BATCH 8
#define N_PROP 8000
#define N_GT 256
#define N_ALL 8256
#define PRE_NMS 1000
#define DETS 300
#define IMG 800.0f
#define DW_CLIP 4.135166556742356f
#define NWORDS 32   // 1000 bits -> 32 u32 words
#define NBINS 8192
#define BIN_SCALE 8192.0f

// Correctly-rounded f32 exp/log via double — matches the numpy reference
// transcendentals bit-for-bit (absmax 0.0 since R1). Do not touch.
__device__ __forceinline__ float exf(float x) { return (float)exp((double)x); }
__device__ __forceinline__ float lgf(float x) { return (float)log((double)x); }

__device__ __forceinline__ int score_bin(float s) {
  int b = (int)(s * BIN_SCALE);
  return (b < 0) ? 0 : (b > NBINS - 1 ? NBINS - 1 : b);
}

// bx[] LDS slot swizzle. [validated R3: SQ_LDS_BANK_CONFLICT 3.5M -> 221K]
__device__ __forceinline__ int bxp(int j) { return j ^ ((j >> 5) & 7); }

// Named scalars for the serial scan (R5-validated: arrays scratch-demote in
// complex kernels; named scalars stay in VGPRs).
#define REP32(F) F(0) F(1) F(2) F(3) F(4) F(5) F(6) F(7) F(8) F(9) F(10) \
  F(11) F(12) F(13) F(14) F(15) F(16) F(17) F(18) F(19) F(20) F(21) F(22) \
  F(23) F(24) F(25) F(26) F(27) F(28) F(29) F(30) F(31)

// STRUCTURE NOTE (R7 post-mortem): 4-kernel chain, launch gaps ~2-3us each
// (R6 vs R7 A/B: merging kernels is noise).  Fences for in-kernel chaining
// cost ~100us (R2-R5).  Remaining lever: per-kernel exec.

// K1: per (b, j) proposal — IoU match, labels, encode, decode, score.
// [validated R9]
__global__ void __launch_bounds__(256)
prep_kernel(const float* __restrict__ prop,
            const float* __restrict__ gt,
            const float* __restrict__ logits,
            const float* __restrict__ breg,
            float* __restrict__ out_labels,
            float* __restrict__ out_regt,
            float* __restrict__ ws_boxes1,
            float* __restrict__ ws_sc) {
  const int b = blockIdx.y;
  const int tid = threadIdx.x;
  __shared__ __align__(16) float4 gsh4[N_GT];
  __shared__ float s_best[32];
  __shared__ int s_bi[32];
  {
    const float4* g4 = (const float4*)(gt + (size_t)b * N_GT * 4);
    gsh4[tid] = g4[tid];   // 256 threads == 256 gt
  }
  __syncthreads();

  const int grp = tid >> 3;              // 32 proposals per block
  const int gl  = tid & 7;
  const int j = blockIdx.x * 32 + grp;   // grid.x = 258 -> j in [0, 8256)

  float x1, y1, x2, y2;
  if (j < N_PROP) {
    const float4 p = ((const float4*)(prop + (size_t)b * N_PROP * 4))[j];
    x1 = p.x; y1 = p.y; x2 = p.z; y2 = p.w;
  } else {
    const float4 g = gsh4[j - N_PROP];
    x1 = g.x; y1 = g.y; x2 = g.z; y2 = g.w;
  }
  const float areaP = (x2 - x1) * (y2 - y1);

  float best = -1.0f; int bi = gl;
  #pragma unroll 4
  for (int t = 0; t < 32; ++t) {
    const int i = gl + (t << 3);         // in-lane ascending -> '>' keeps first
    const float4 g = gsh4[i];            // ONE ds_read_b128, conflict-free
    const float ga = (g.z - g.x) * (g.w - g.y);
    const float w = fmaxf(fminf(g.z, x2) - fmaxf(g.x, x1), 0.0f);
    const float h = fmaxf(fminf(g.w, y2) - fmaxf(g.y, y1), 0.0f);
    const float inter = w * h;
    const float iou = inter / (ga + areaP - inter);
    if (iou > best) { best = iou; bi = i; }
  }
  #pragma unroll
  for (int m = 1; m < 8; m <<= 1) {      // (max, min-index) == first-max
    const float ov = __shfl_xor(best, m, 64);
    const int   oi = __shfl_xor(bi,  m, 64);
    if (ov > best || (ov == best && oi < bi)) { best = ov; bi = oi; }
  }
  if (gl == 0) { s_best[grp] = best; s_bi[grp] = bi; }
  __syncthreads();

  if (tid < 32) {                        // single wave, 32 active lanes
    const int j2 = blockIdx.x * 32 + tid;
    const float bst = s_best[tid];
    const int   gi  = s_bi[tid];

    float px1, py1, px2, py2;
    if (j2 < N_PROP) {
      const float4 p = ((const float4*)(prop + (size_t)b * N_PROP * 4))[j2];
      px1 = p.x; py1 = p.y; px2 = p.z; py2 = p.w;
    } else {
      const float4 g = gsh4[j2 - N_PROP];
      px1 = g.x; py1 = g.y; px2 = g.z; py2 = g.w;
    }

    out_labels[(size_t)b * N_ALL + j2] = (bst < 0.5f) ? 0.0f : 1.0f;

    const float pw = px2 - px1, ph = py2 - py1;
    const float pcx = px1 + 0.5f * pw, pcy = py1 + 0.5f * ph;
    const float4 gb = gsh4[gi];
    const float gw = gb.z - gb.x, gh = gb.w - gb.y;
    const float gcx = gb.x + 0.5f * gw, gcy = gb.y + 0.5f * gh;
    float4 rt;
    rt.x = 10.0f * (gcx - pcx) / pw;
    rt.y = 10.0f * (gcy - pcy) / ph;
    rt.z = 5.0f * lgf(gw / pw);
    rt.w = 5.0f * lgf(gh / ph);
    ((float4*)out_regt)[(size_t)b * N_ALL + j2] = rt;

    const float4 r = *(const float4*)(breg + (((size_t)b * N_ALL + j2) * 8 + 4));
    const float dx = r.x / 10.0f, dy = r.y / 10.0f;
    const float dw = fminf(r.z / 5.0f, DW_CLIP);
    const float dh = fminf(r.w / 5.0f, DW_CLIP);
    const float cx = dx * pw + pcx, cy = dy * ph + pcy;
    const float w2 = exf(dw) * pw, h2 = exf(dh) * ph;
    float4 bb;
    bb.x = fminf(fmaxf(cx - 0.5f * w2, 0.0f), IMG);
    bb.y = fminf(fmaxf(cy - 0.5f * h2, 0.0f), IMG);
    bb.z = fminf(fmaxf(cx + 0.5f * w2, 0.0f), IMG);
    bb.w = fminf(fmaxf(cy + 0.5f * h2, 0.0f), IMG);
    ((float4*)ws_boxes1)[(size_t)b * N_ALL + j2] = bb;

    const float2 lg = *(const float2*)(logits + ((size_t)b * N_ALL + j2) * 2);
    const float m = fmaxf(lg.x, lg.y);
    const float e0 = exf(lg.x - m), e1 = exf(lg.y - m);
    const float s = e1 / (e0 + e1);
    ws_sc[(size_t)b * N_ALL + j2] = (s > 0.05f) ? s : -1.0f;
  }
}

// K2 (R11): fused hist + threshold + HISTOGRAM-RANKED scatter + exact rank.
// [validated R11: absmax 0.0]
__global__ void __launch_bounds__(1024)
select_rank_kernel(const float* __restrict__ ws_sc,
                   const float* __restrict__ ws_boxes1,
                   float* __restrict__ top_s,
                   float* __restrict__ top_b) {
  const int b = blockIdx.x;
  const int tid = threadIdx.x;
  const int lane = tid & 63, wid = tid >> 6;
  __shared__ __align__(16) float ssc[N_ALL];          // 33.0 KB
  __shared__ unsigned hist[NBINS];                    // 32.0 KB
  __shared__ __align__(16) float sc2[N_ALL];          // 33.0 KB
  __shared__ unsigned short idx2[N_ALL];              // 16.5 KB
  __shared__ int s_wt[16], s_wx[16];
  __shared__ int s_T, s_Nc;

  {
    const float4* g = (const float4*)(ws_sc + (size_t)b * N_ALL);
    float4* s4 = (float4*)ssc;
    float4 a0 = g[tid], a1 = g[tid + 1024];
    float4 a2 = make_float4(0.f, 0.f, 0.f, 0.f);
    const bool g2 = (tid + 2048) < (N_ALL / 4);   // 2064
    if (g2) a2 = g[tid + 2048];
    s4[tid] = a0; s4[tid + 1024] = a1;
    if (g2) s4[tid + 2048] = a2;
  }
  #pragma unroll
  for (int i = 0; i < NBINS / 1024; ++i) hist[tid + i * 1024] = 0u;
  __syncthreads();
  for (int k = tid; k < N_ALL; k += 1024)
    atomicAdd(&hist[score_bin(ssc[k])], 1u);
  __syncthreads();

  // thread tid owns bins [tid*8, tid*8+8)
  int local = 0;
  #pragma unroll
  for (int i = 0; i < NBINS / 1024; ++i) local += (int)hist[tid * (NBINS / 1024) + i];

  int incl = local;                       // suffix-inclusive within wave
  #pragma unroll
  for (int off = 1; off < 64; off <<= 1) {
    const int u = __shfl_down(incl, off);
    incl += (lane + off < 64) ? u : 0;
  }
  if (lane == 0) s_wt[wid] = incl;
  __syncthreads();
  if (tid < 16) {                         // suffix across the 16 waves
    const int v = s_wt[tid];
    int inc2 = v;
    #pragma unroll
    for (int off = 1; off < 16; off <<= 1) {
      const int u = __shfl_down(inc2, off);
      inc2 += (tid + off < 16) ? u : 0;
    }
    s_wx[tid] = inc2 - v;
  }
  __syncthreads();
  const int sa = (incl - local) + s_wx[wid];  // count in bins above my block

  // descending in-place walk: hist[bin] := count strictly above bin;
  // detect threshold crossing (unique thread) on the way.
  {
    int above = sa;
    const int hi = tid * (NBINS / 1024) + (NBINS / 1024) - 1;
    #pragma unroll
    for (int i = 0; i < NBINS / 1024; ++i) {
      const int bin = hi - i;
      const int c = (int)hist[bin];
      if (above < PRE_NMS && above + c >= PRE_NMS) { s_T = bin; s_Nc = above + c; }
      hist[bin] = (unsigned)above;
      above += c;
    }
  }
  __syncthreads();
  const int T = s_T;
  const int Nc = s_Nc;                    // >= PRE_NMS always (total = 8256)

  // scatter: slot = rank_base(bin) + arbitrary intra-bin offset
  for (int k = tid; k < N_ALL; k += 1024) {
    const float v = ssc[k];
    const int bb = score_bin(v);
    if (bb >= T) {
      const int slot = (int)atomicAdd(&hist[bb], 1u);
      sc2[slot] = v;
      idx2[slot] = (unsigned short)k;
    }
  }
  __syncthreads();

  // resolve exact rank per slot (same-bin groups are contiguous; avg ~1 elem)
  float* tsb = top_s + (size_t)b * PRE_NMS;
  float4* tbb = (float4*)top_b + (size_t)b * PRE_NMS;
  const float4* bx = (const float4*)ws_boxes1 + (size_t)b * N_ALL;
  for (int s = tid; s < Nc; s += 1024) {
    const float my = sc2[s];
    const int myb = score_bin(my);
    const int myi = (int)idx2[s];
    int gl = s;
    while (gl > 0 && score_bin(sc2[gl - 1]) == myb) --gl;
    int rank = gl;
    for (int k2 = gl; k2 < Nc; ++k2) {
      const float v = sc2[k2];
      if (score_bin(v) != myb) break;
      if (k2 == s) continue;
      rank += (int)((v > my) | ((v == my) & ((int)idx2[k2] < myi)));
    }
    if (rank < PRE_NMS) {
      tsb[rank] = my;
      tbb[rank] = bx[myi];
    }
  }
}

// K3a: standalone suppression-mask build.  [validated R2 structure +
// R3 bxp swizzle]
__global__ void mask_kernel(const float* __restrict__ top_b,
                            unsigned* __restrict__ ws_mask) {
  const int b = blockIdx.y;
  __shared__ __align__(16) float4 bx[PRE_NMS];
  const int tid = threadIdx.x;
  {
    const float4* gb = (const float4*)top_b + (size_t)b * PRE_NMS;
    float4 v0 = gb[tid], v1 = gb[tid + 256], v2 = gb[tid + 512];
    float4 v3 = make_float4(0.f, 0.f, 0.f, 0.f);
    const bool g3 = (tid + 768) < PRE_NMS;
    if (g3) v3 = gb[tid + 768];
    bx[bxp(tid)] = v0; bx[bxp(tid + 256)] = v1; bx[bxp(tid + 512)] = v2;
    if (g3) bx[bxp(tid + 768)] = v3;
  }
  __syncthreads();
  const int idx = blockIdx.x * blockDim.x + tid;
  if (idx >= PRE_NMS * NWORDS) return;
  const int i = idx >> 5;
  const int w = idx & 31;
  const float4 bi = bx[bxp(i)];
  const float ai = (bi.z - bi.x) * (bi.w - bi.y);
  unsigned bits = 0u;
  const int j0 = w * 32;
  #pragma unroll 8
  for (int jj = 0; jj < 32; ++jj) {
    const int j = j0 + jj;
    if (j > i && j < PRE_NMS) {
      const float4 bj = bx[bxp(j)];
      const float aj = (bj.z - bj.x) * (bj.w - bj.y);
      const float ww = fmaxf(fminf(bi.z, bj.z) - fmaxf(bi.x, bj.x), 0.0f);
      const float hh = fmaxf(fminf(bi.w, bj.w) - fmaxf(bi.y, bj.y), 0.0f);
      const float inter = ww * hh;
      const float iou = inter / (ai + aj - inter);  // NaN>0.5 false
      if (iou > 0.5f) bits |= (1u << jj);
    }
  }
  ws_mask[((size_t)b * PRE_NMS + i) * NWORDS + w] = bits;
}

// K3b: serial scan + det-300 selection.  [recurrence validated R0-R7]
// R8: DETS-early-exit — word `win` of keep is FINAL after window `win`
// (== the chain's sw value: keep_win &= ~sup_win where sup_win's word-win
// bits are exactly the rw&m used in the chain).  Once the finalized prefix
// holds >= 300 kept rows, later windows cannot affect the output: kept rows
// there get pos>=300 (no write) and filler needs tot+(k-pos)<300 which is
// impossible with tot>=300.  Break is wave-uniform (scalar sw/c300).
__global__ void __launch_bounds__(256)
scan_kernel(const unsigned* __restrict__ ws_mask,
            const float* __restrict__ top_s,
            const float* __restrict__ top_b,
            float* __restrict__ out_detb,
            float* __restrict__ out_dets) {
  const int b = blockIdx.x;
  const int tid = threadIdx.x;
  __shared__ __align__(16) unsigned smask[PRE_NMS * NWORDS];  // 125 KiB
  __shared__ int s_npos;
  __shared__ unsigned s_flw[NWORDS];
  __shared__ int s_pref[NWORDS + 1];
  const float* ts = top_s + (size_t)b * PRE_NMS;

  if (tid == 0) s_npos = 0;
  // deep-pipelined stage: 8000 uint4, 4 groups x 8 loads-to-regs then store
  {
    const uint4* gm = (const uint4*)(ws_mask + (size_t)b * PRE_NMS * NWORDS);
    uint4* sm4 = (uint4*)smask;
    #pragma unroll
    for (int gs = 0; gs < 4; ++gs) {
      const int k0 = gs * 2048 + tid;
      uint4 t0 = gm[k0],        t1 = gm[k0 + 256],  t2 = gm[k0 + 512];
      uint4 t3 = gm[k0 + 768],  t4 = gm[k0 + 1024], t5 = gm[k0 + 1280];
      uint4 t6 = gm[k0 + 1536];
      uint4 t7 = make_uint4(0u, 0u, 0u, 0u);
      const bool g7 = (k0 + 1792) < (PRE_NMS * NWORDS / 4);   // 8000
      if (g7) t7 = gm[k0 + 1792];
      sm4[k0] = t0;        sm4[k0 + 256] = t1;  sm4[k0 + 512] = t2;
      sm4[k0 + 768] = t3;  sm4[k0 + 1024] = t4; sm4[k0 + 1280] = t5;
      sm4[k0 + 1536] = t6;
      if (g7) sm4[k0 + 1792] = t7;
    }
  }
  int cnt = 0;
  for (int k = tid; k < PRE_NMS; k += 256) cnt += (ts[k] > 0.0f) ? 1 : 0;
  __syncthreads();                     // staging visible + s_npos zeroed
  if (cnt) atomicAdd(&s_npos, cnt);
  __syncthreads();                     // n_pos final BEFORE the serial scan
  const int n_pos = s_npos;

  unsigned keep = 0u;
  if (tid < 64) {                      // wave 0: serial greedy scan
    const int lane = tid;
    const int lw = lane & 31;          // word index (upper half mirrors)
    keep = (lane < NWORDS) ? ((lane == 31) ? 0xFFu : 0xFFFFFFFFu) : 0u;
#define DECLA(J) unsigned rA##J;
    REP32(DECLA)
#undef DECLA
    int c300 = 0;
    for (int win = 0; win < 32; ++win) {
      unsigned sw = (unsigned)__builtin_amdgcn_readlane((int)keep, win);
      if (sw) {                        // wave-uniform skip of dead windows
        const int base = win * 32;
#define LOADA(J) rA##J = smask[(base + J) * NWORDS + lw];
        REP32(LOADA)
#undef LOADA
        unsigned sup = 0u;
#define STEPJ(J) { \
        const unsigned mJ = 0u - ((sw >> J) & 1u); \
        const unsigned rwJ = (unsigned)__builtin_amdgcn_readlane((int)rA##J, win); \
        sw &= ~(rwJ & mJ); \
        sup |= (rA##J & mJ); }
        REP32(STEPJ)
#undef STEPJ
        keep &= ~sup;                  // one update per window
      }
      // count finalized keeps among valid rows of this window; break at 300
      int npw = n_pos - win * 32;
      npw = (npw < 0) ? 0 : (npw > 32 ? 32 : npw);
      const unsigned npmw = (npw >= 32) ? 0xFFFFFFFFu : ((1u << npw) - 1u);
      c300 += __popc(sw & npmw);
      if (c300 >= DETS) break;         // wave-uniform (scalar c300)
    }
  }
  __syncthreads();
  if (tid < NWORDS) {                  // wave 0 still holds keep
    const int lo = tid * 32;
    int np = n_pos - lo;
    np = (np < 0) ? 0 : (np > 32 ? 32 : np);
    const unsigned npm = (np >= 32) ? 0xFFFFFFFFu : ((1u << np) - 1u);
    s_flw[tid] = keep & npm;           // keep already 0 beyond bit 999
  }
  __syncthreads();
  if (tid == 0) {
    int s = 0;
    #pragma unroll
    for (int w = 0; w < NWORDS; ++w) { s_pref[w] = s; s += __popc(s_flw[w]); }
    s_pref[NWORDS] = s;
  }
  __syncthreads();
  const int tot = s_pref[NWORDS];

  for (int k = tid; k < PRE_NMS; k += 256) {
    const unsigned fw = s_flw[k >> 5];
    const int fbit = (int)((fw >> (k & 31)) & 1u);
    const int pos = s_pref[k >> 5] + __popc(fw & ((1u << (k & 31)) - 1u));
    int slot = -1; float sval = 0.0f;
    if (fbit) {
      if (pos < DETS) { slot = pos; sval = ts[k]; }
    } else {
      const int s2 = tot + (k - pos);
      if (s2 < DETS) { slot = s2; sval = -1.0f; }
    }
    if (slot >= 0) {
      out_dets[(size_t)b * DETS + slot] = sval;
      ((float4*)out_detb)[(size_t)b * DETS + slot] =
          ((const float4*)top_b)[(size_t)b * PRE_NMS + k];
    }
  }
}

extern "C" void kernel_launch(void* const* d_in, const int* in_sizes, int n_in,
                              void* d_out, int out_size, void* d_ws, size_t ws_size,
                              hipStream_t stream) {
  const float* prop   = (const float*)d_in[0];
  const float* gt     = (const float*)d_in[1];
  const float* logits = (const float*)d_in[2];
  const float* breg   = (const float*)d_in[3];

  float* out        = (float*)d_out;
  float* out_labels = out;                                   // B*N_ALL
  float* out_regt   = out + (size_t)BATCH * N_ALL;           // B*N_ALL*4
  float* out_detb   = out_regt + (size_t)BATCH * N_ALL * 4;  // B*DETS*4
  float* out_dets   = out_detb + (size_t)BATCH * DETS * 4;   // B*DETS

  float* ws_boxes1 = (float*)d_ws;                            // B*N_ALL*4
  float* ws_sc     = ws_boxes1 + (size_t)BATCH * N_ALL * 4;   // B*N_ALL
  float* ws_tops   = ws_sc + (size_t)BATCH * N_ALL;           // B*PRE_NMS
  float* ws_topb   = ws_tops + (size_t)BATCH * PRE_NMS;       // B*PRE_NMS*4
  unsigned* ws_mask = (unsigned*)(ws_topb + (size_t)BATCH * PRE_NMS * 4); // B*1000*32

  hipLaunchKernelGGL(prep_kernel, dim3(258, BATCH), dim3(256), 0, stream,
                     prop, gt, logits, breg, out_labels, out_regt, ws_boxes1, ws_sc);
  hipLaunchKernelGGL(select_rank_kernel, dim3(BATCH), dim3(1024), 0, stream,
                     ws_sc, ws_boxes1, ws_tops, ws_topb);
  dim3 gridm((PRE_NMS * NWORDS + 255) / 256, BATCH);
  hipLaunchKernelGGL(mask_kernel, gridm, dim3(256), 0, stream,
                     ws_topb, ws_mask);
  hipLaunchKernelGGL(scan_kernel, dim3(BATCH), dim3(256), 0, stream,
                     ws_mask, ws_tops, ws_topb, out_detb, out_dets);
}

// Round 9
// 56.224 us; speedup vs baseline: 1.1851x; 1.0342x over previous
//
#include <hip/hip_runtime.h>
#include <math.h>

#pragma clang fp contract(off)

#define BATCH 8
#define N_PROP 8000
#define N_GT 256
#define N_ALL 8256
#define PRE_NMS 1000
#define DETS 300
#define IMG 800.0f
#define DW_CLIP 4.135166556742356f
#define NWORDS 32   // 1000 bits -> 32 u32 words
#define NBINS 8192
#define BIN_SCALE 8192.0f
#define PREP_PER_BATCH 65   // ceil(8256/128) 128-proposal blocks
#define SEL_BLOCKS 8

// Correctly-rounded f32 exp/log via double — matches the numpy reference
// transcendentals bit-for-bit (absmax 0.0 since R1). Do not touch.
__device__ __forceinline__ float exf(float x) { return (float)exp((double)x); }
__device__ __forceinline__ float lgf(float x) { return (float)log((double)x); }

__device__ __forceinline__ int score_bin(float s) {
  int b = (int)(s * BIN_SCALE);
  return (b < 0) ? 0 : (b > NBINS - 1 ? NBINS - 1 : b);
}

// bx[] LDS slot swizzle. [validated R3: SQ_LDS_BANK_CONFLICT 3.5M -> 221K]
__device__ __forceinline__ int bxp(int j) { return j ^ ((j >> 5) & 7); }

// Named scalars for the serial scan (R5-validated: arrays scratch-demote in
// complex kernels; named scalars stay in VGPRs).
#define REP32(F) F(0) F(1) F(2) F(3) F(4) F(5) F(6) F(7) F(8) F(9) F(10) \
  F(11) F(12) F(13) F(14) F(15) F(16) F(17) F(18) F(19) F(20) F(21) F(22) \
  F(23) F(24) F(25) F(26) F(27) F(28) F(29) F(30) F(31)

// R9 STRUCTURE: [select || prep] -> mask -> scan (2 gaps).
// R7 validated (absmax 0.0) that select can compute scores from logits and
// lazily decode only candidate boxes -> prep (match/labels/encode; terminal
// outputs) is INDEPENDENT of the detection chain.  The 8 narrow select
// blocks are dispatched FIRST (blockIdx.x < 8) so they start immediately;
// 520 wide prep blocks fill the other CUs and finish inside select's shadow.
// (R7's mistake: merged prep with mask — both wide+short, nothing hidden.)

// K1: fused [select_rank (idx<8)] || [prep match+labels+encode (idx>=8)].
__global__ void __launch_bounds__(1024)
fused_select_prep_kernel(const float* __restrict__ prop,
                         const float* __restrict__ gt,
                         const float* __restrict__ logits,
                         const float* __restrict__ breg,
                         float* __restrict__ out_labels,
                         float* __restrict__ out_regt,
                         float* __restrict__ top_s,
                         float* __restrict__ top_b) {
  const int idx = blockIdx.x;
  const int tid = threadIdx.x;
  // select-role LDS (~119.5 KB) + prep-role LDS (~5.1 KB) = ~124.6 KB < 160
  __shared__ __align__(16) float ssc[N_ALL];          // 33.0 KB
  __shared__ unsigned hist[NBINS];                    // 32.0 KB
  __shared__ __align__(16) float sc2[N_ALL];          // 33.0 KB
  __shared__ unsigned short idx2[N_ALL];              // 16.5 KB
  __shared__ __align__(16) float4 gsh[N_GT];          //  4.0 KB
  __shared__ int s_wt[16], s_wx[16];
  __shared__ int s_T, s_Nc;
  __shared__ __align__(16) float4 gsh4[N_GT];         //  4.0 KB (prep)
  __shared__ float s_best[128];
  __shared__ int s_bi[128];

  if (idx < SEL_BLOCKS) {
    // ================= SELECT ROLE (R7-validated verbatim) =================
    const int b = idx;
    const int lane = tid & 63, wid = tid >> 6;

    if (tid < N_GT) gsh[tid] = ((const float4*)(gt + (size_t)b * N_GT * 4))[tid];

    // thresholded scores from logits (bit-exact vs old prep epilogue)
    for (int k = tid; k < N_ALL; k += 1024) {
      const float2 lg = *(const float2*)(logits + ((size_t)b * N_ALL + k) * 2);
      const float m = fmaxf(lg.x, lg.y);
      const float e0 = exf(lg.x - m), e1 = exf(lg.y - m);
      const float s = e1 / (e0 + e1);
      ssc[k] = (s > 0.05f) ? s : -1.0f;
    }
    #pragma unroll
    for (int i = 0; i < NBINS / 1024; ++i) hist[tid + i * 1024] = 0u;
    __syncthreads();
    for (int k = tid; k < N_ALL; k += 1024)
      atomicAdd(&hist[score_bin(ssc[k])], 1u);
    __syncthreads();

    // thread tid owns bins [tid*8, tid*8+8)
    int local = 0;
    #pragma unroll
    for (int i = 0; i < NBINS / 1024; ++i) local += (int)hist[tid * (NBINS / 1024) + i];

    int incl = local;                       // suffix-inclusive within wave
    #pragma unroll
    for (int off = 1; off < 64; off <<= 1) {
      const int u = __shfl_down(incl, off);
      incl += (lane + off < 64) ? u : 0;
    }
    if (lane == 0) s_wt[wid] = incl;
    __syncthreads();
    if (tid < 16) {                         // suffix across the 16 waves
      const int v = s_wt[tid];
      int inc2 = v;
      #pragma unroll
      for (int off = 1; off < 16; off <<= 1) {
        const int u = __shfl_down(inc2, off);
        inc2 += (tid + off < 16) ? u : 0;
      }
      s_wx[tid] = inc2 - v;
    }
    __syncthreads();
    const int sa = (incl - local) + s_wx[wid];

    {
      int above = sa;
      const int hi = tid * (NBINS / 1024) + (NBINS / 1024) - 1;
      #pragma unroll
      for (int i = 0; i < NBINS / 1024; ++i) {
        const int bin = hi - i;
        const int c = (int)hist[bin];
        if (above < PRE_NMS && above + c >= PRE_NMS) { s_T = bin; s_Nc = above + c; }
        hist[bin] = (unsigned)above;
        above += c;
      }
    }
    __syncthreads();
    const int T = s_T;
    const int Nc = s_Nc;

    for (int k = tid; k < N_ALL; k += 1024) {
      const float v = ssc[k];
      const int bb = score_bin(v);
      if (bb >= T) {
        const int slot = (int)atomicAdd(&hist[bb], 1u);
        sc2[slot] = v;
        idx2[slot] = (unsigned short)k;
      }
    }
    __syncthreads();

    // exact rank + lazy decode of winning boxes (R7-validated bit-exact)
    float* tsb = top_s + (size_t)b * PRE_NMS;
    float4* tbb = (float4*)top_b + (size_t)b * PRE_NMS;
    for (int s = tid; s < Nc; s += 1024) {
      const float my = sc2[s];
      const int myb = score_bin(my);
      const int myi = (int)idx2[s];
      int gl = s;
      while (gl > 0 && score_bin(sc2[gl - 1]) == myb) --gl;
      int rank = gl;
      for (int k2 = gl; k2 < Nc; ++k2) {
        const float v = sc2[k2];
        if (score_bin(v) != myb) break;
        if (k2 == s) continue;
        rank += (int)((v > my) | ((v == my) & ((int)idx2[k2] < myi)));
      }
      if (rank < PRE_NMS) {
        tsb[rank] = my;
        float4 pb;
        if (myi < N_PROP) pb = ((const float4*)(prop + (size_t)b * N_PROP * 4))[myi];
        else              pb = gsh[myi - N_PROP];
        const float pw = pb.z - pb.x, ph = pb.w - pb.y;
        const float pcx = pb.x + 0.5f * pw, pcy = pb.y + 0.5f * ph;
        const float4 r = *(const float4*)(breg + (((size_t)b * N_ALL + myi) * 8 + 4));
        const float dx = r.x / 10.0f, dy = r.y / 10.0f;
        const float dw = fminf(r.z / 5.0f, DW_CLIP);
        const float dh = fminf(r.w / 5.0f, DW_CLIP);
        const float cx = dx * pw + pcx, cy = dy * ph + pcy;
        const float w2 = exf(dw) * pw, h2 = exf(dh) * ph;
        float4 bb;
        bb.x = fminf(fmaxf(cx - 0.5f * w2, 0.0f), IMG);
        bb.y = fminf(fmaxf(cy - 0.5f * h2, 0.0f), IMG);
        bb.z = fminf(fmaxf(cx + 0.5f * w2, 0.0f), IMG);
        bb.w = fminf(fmaxf(cy + 0.5f * h2, 0.0f), IMG);
        tbb[rank] = bb;
      }
    }
  } else {
    // ====== PREP ROLE: IoU match + labels + encode (terminal outputs) ======
    // 1024-thread geometry: 128 proposals/block, 8 lanes each.  Numerically
    // identical to the R6-validated prep (same expressions, same in-lane-
    // ascending first-max reduction; groups never cross wave boundaries).
    const int pbx = idx - SEL_BLOCKS;          // [0, 520)
    const int b = pbx / PREP_PER_BATCH;
    const int blk = pbx - b * PREP_PER_BATCH;  // [0, 65)
    {
      if (tid < N_GT)
        gsh4[tid] = ((const float4*)(gt + (size_t)b * N_GT * 4))[tid];
    }
    __syncthreads();

    const int grp = tid >> 3;              // [0, 128)
    const int gl  = tid & 7;
    const int j0b = blk * 128;
    const int j = j0b + grp;               // may exceed N_ALL in last block
    const bool jv = (j < N_ALL);

    float x1, y1, x2, y2;
    if (jv && j < N_PROP) {
      const float4 p = ((const float4*)(prop + (size_t)b * N_PROP * 4))[j];
      x1 = p.x; y1 = p.y; x2 = p.z; y2 = p.w;
    } else if (jv) {
      const float4 g = gsh4[j - N_PROP];
      x1 = g.x; y1 = g.y; x2 = g.z; y2 = g.w;
    } else {
      const float4 g = gsh4[0];            // inert dummy (no stores later)
      x1 = g.x; y1 = g.y; x2 = g.z; y2 = g.w;
    }
    const float areaP = (x2 - x1) * (y2 - y1);

    float best = -1.0f; int bi = gl;
    #pragma unroll 4
    for (int t = 0; t < 32; ++t) {
      const int i = gl + (t << 3);         // in-lane ascending -> '>' keeps first
      const float4 g = gsh4[i];
      const float ga = (g.z - g.x) * (g.w - g.y);
      const float w = fmaxf(fminf(g.z, x2) - fmaxf(g.x, x1), 0.0f);
      const float h = fmaxf(fminf(g.w, y2) - fmaxf(g.y, y1), 0.0f);
      const float inter = w * h;
      const float iou = inter / (ga + areaP - inter);
      if (iou > best) { best = iou; bi = i; }
    }
    #pragma unroll
    for (int m = 1; m < 8; m <<= 1) {      // (max, min-index) == first-max
      const float ov = __shfl_xor(best, m, 64);
      const int   oi = __shfl_xor(bi,  m, 64);
      if (ov > best || (ov == best && oi < bi)) { best = ov; bi = oi; }
    }
    if (gl == 0) { s_best[grp] = best; s_bi[grp] = bi; }
    __syncthreads();

    if (tid < 128) {                       // 2 waves, one proposal each
      const int j2 = j0b + tid;
      if (j2 < N_ALL) {
        const float bst = s_best[tid];
        const int   gi  = s_bi[tid];

        float px1, py1, px2, py2;
        if (j2 < N_PROP) {
          const float4 p = ((const float4*)(prop + (size_t)b * N_PROP * 4))[j2];
          px1 = p.x; py1 = p.y; px2 = p.z; py2 = p.w;
        } else {
          const float4 g = gsh4[j2 - N_PROP];
          px1 = g.x; py1 = g.y; px2 = g.z; py2 = g.w;
        }

        out_labels[(size_t)b * N_ALL + j2] = (bst < 0.5f) ? 0.0f : 1.0f;

        const float pw = px2 - px1, ph = py2 - py1;
        const float pcx = px1 + 0.5f * pw, pcy = py1 + 0.5f * ph;
        const float4 gb = gsh4[gi];
        const float gw = gb.z - gb.x, gh = gb.w - gb.y;
        const float gcx = gb.x + 0.5f * gw, gcy = gb.y + 0.5f * gh;
        float4 rt;
        rt.x = 10.0f * (gcx - pcx) / pw;
        rt.y = 10.0f * (gcy - pcy) / ph;
        rt.z = 5.0f * lgf(gw / pw);
        rt.w = 5.0f * lgf(gh / ph);
        ((float4*)out_regt)[(size_t)b * N_ALL + j2] = rt;
      }
    }
  }
}

// K2: suppression-mask build.  [validated R2 structure + R3 bxp swizzle]
__global__ void mask_kernel(const float* __restrict__ top_b,
                            unsigned* __restrict__ ws_mask) {
  const int b = blockIdx.y;
  __shared__ __align__(16) float4 bx[PRE_NMS];
  const int tid = threadIdx.x;
  {
    const float4* gb = (const float4*)top_b + (size_t)b * PRE_NMS;
    float4 v0 = gb[tid], v1 = gb[tid + 256], v2 = gb[tid + 512];
    float4 v3 = make_float4(0.f, 0.f, 0.f, 0.f);
    const bool g3 = (tid + 768) < PRE_NMS;
    if (g3) v3 = gb[tid + 768];
    bx[bxp(tid)] = v0; bx[bxp(tid + 256)] = v1; bx[bxp(tid + 512)] = v2;
    if (g3) bx[bxp(tid + 768)] = v3;
  }
  __syncthreads();
  const int idx = blockIdx.x * blockDim.x + tid;
  if (idx >= PRE_NMS * NWORDS) return;
  const int i = idx >> 5;
  const int w = idx & 31;
  const float4 bi = bx[bxp(i)];
  const float ai = (bi.z - bi.x) * (bi.w - bi.y);
  unsigned bits = 0u;
  const int j0 = w * 32;
  #pragma unroll 8
  for (int jj = 0; jj < 32; ++jj) {
    const int j = j0 + jj;
    if (j > i && j < PRE_NMS) {
      const float4 bj = bx[bxp(j)];
      const float aj = (bj.z - bj.x) * (bj.w - bj.y);
      const float ww = fmaxf(fminf(bi.z, bj.z) - fmaxf(bi.x, bj.x), 0.0f);
      const float hh = fmaxf(fminf(bi.w, bj.w) - fmaxf(bi.y, bj.y), 0.0f);
      const float inter = ww * hh;
      const float iou = inter / (ai + aj - inter);  // NaN>0.5 false
      if (iou > 0.5f) bits |= (1u << jj);
    }
  }
  ws_mask[((size_t)b * PRE_NMS + i) * NWORDS + w] = bits;
}

// K3: serial scan + det-300 selection.  [recurrence validated R0-R8;
// DETS-early-exit validated R8: absmax 0.0, -7us]
__global__ void __launch_bounds__(256)
scan_kernel(const unsigned* __restrict__ ws_mask,
            const float* __restrict__ top_s,
            const float* __restrict__ top_b,
            float* __restrict__ out_detb,
            float* __restrict__ out_dets) {
  const int b = blockIdx.x;
  const int tid = threadIdx.x;
  __shared__ __align__(16) unsigned smask[PRE_NMS * NWORDS];  // 125 KiB
  __shared__ int s_npos;
  __shared__ unsigned s_flw[NWORDS];
  __shared__ int s_pref[NWORDS + 1];
  const float* ts = top_s + (size_t)b * PRE_NMS;

  if (tid == 0) s_npos = 0;
  // deep-pipelined stage: 8000 uint4, 4 groups x 8 loads-to-regs then store
  {
    const uint4* gm = (const uint4*)(ws_mask + (size_t)b * PRE_NMS * NWORDS);
    uint4* sm4 = (uint4*)smask;
    #pragma unroll
    for (int gs = 0; gs < 4; ++gs) {
      const int k0 = gs * 2048 + tid;
      uint4 t0 = gm[k0],        t1 = gm[k0 + 256],  t2 = gm[k0 + 512];
      uint4 t3 = gm[k0 + 768],  t4 = gm[k0 + 1024], t5 = gm[k0 + 1280];
      uint4 t6 = gm[k0 + 1536];
      uint4 t7 = make_uint4(0u, 0u, 0u, 0u);
      const bool g7 = (k0 + 1792) < (PRE_NMS * NWORDS / 4);   // 8000
      if (g7) t7 = gm[k0 + 1792];
      sm4[k0] = t0;        sm4[k0 + 256] = t1;  sm4[k0 + 512] = t2;
      sm4[k0 + 768] = t3;  sm4[k0 + 1024] = t4; sm4[k0 + 1280] = t5;
      sm4[k0 + 1536] = t6;
      if (g7) sm4[k0 + 1792] = t7;
    }
  }
  int cnt = 0;
  for (int k = tid; k < PRE_NMS; k += 256) cnt += (ts[k] > 0.0f) ? 1 : 0;
  __syncthreads();                     // staging visible + s_npos zeroed
  if (cnt) atomicAdd(&s_npos, cnt);
  __syncthreads();                     // n_pos final BEFORE the serial scan
  const int n_pos = s_npos;

  unsigned keep = 0u;
  if (tid < 64) {                      // wave 0: serial greedy scan
    const int lane = tid;
    const int lw = lane & 31;          // word index (upper half mirrors)
    keep = (lane < NWORDS) ? ((lane == 31) ? 0xFFu : 0xFFFFFFFFu) : 0u;
#define DECLA(J) unsigned rA##J;
    REP32(DECLA)
#undef DECLA
    int c300 = 0;
    for (int win = 0; win < 32; ++win) {
      unsigned sw = (unsigned)__builtin_amdgcn_readlane((int)keep, win);
      if (sw) {                        // wave-uniform skip of dead windows
        const int base = win * 32;
#define LOADA(J) rA##J = smask[(base + J) * NWORDS + lw];
        REP32(LOADA)
#undef LOADA
        unsigned sup = 0u;
#define STEPJ(J) { \
        const unsigned mJ = 0u - ((sw >> J) & 1u); \
        const unsigned rwJ = (unsigned)__builtin_amdgcn_readlane((int)rA##J, win); \
        sw &= ~(rwJ & mJ); \
        sup |= (rA##J & mJ); }
        REP32(STEPJ)
#undef STEPJ
        keep &= ~sup;                  // one update per window
      }
      // count finalized keeps among valid rows; break once 300 are final
      int npw = n_pos - win * 32;
      npw = (npw < 0) ? 0 : (npw > 32 ? 32 : npw);
      const unsigned npmw = (npw >= 32) ? 0xFFFFFFFFu : ((1u << npw) - 1u);
      c300 += __popc(sw & npmw);
      if (c300 >= DETS) break;         // wave-uniform (scalar c300)
    }
  }
  __syncthreads();
  if (tid < NWORDS) {                  // wave 0 still holds keep
    const int lo = tid * 32;
    int np = n_pos - lo;
    np = (np < 0) ? 0 : (np > 32 ? 32 : np);
    const unsigned npm = (np >= 32) ? 0xFFFFFFFFu : ((1u << np) - 1u);
    s_flw[tid] = keep & npm;           // keep already 0 beyond bit 999
  }
  __syncthreads();
  if (tid == 0) {
    int s = 0;
    #pragma unroll
    for (int w = 0; w < NWORDS; ++w) { s_pref[w] = s; s += __popc(s_flw[w]); }
    s_pref[NWORDS] = s;
  }
  __syncthreads();
  const int tot = s_pref[NWORDS];

  for (int k = tid; k < PRE_NMS; k += 256) {
    const unsigned fw = s_flw[k >> 5];
    const int fbit = (int)((fw >> (k & 31)) & 1u);
    const int pos = s_pref[k >> 5] + __popc(fw & ((1u << (k & 31)) - 1u));
    int slot = -1; float sval = 0.0f;
    if (fbit) {
      if (pos < DETS) { slot = pos; sval = ts[k]; }
    } else {
      const int s2 = tot + (k - pos);
      if (s2 < DETS) { slot = s2; sval = -1.0f; }
    }
    if (slot >= 0) {
      out_dets[(size_t)b * DETS + slot] = sval;
      ((float4*)out_detb)[(size_t)b * DETS + slot] =
          ((const float4*)top_b)[(size_t)b * PRE_NMS + k];
    }
  }
}

extern "C" void kernel_launch(void* const* d_in, const int* in_sizes, int n_in,
                              void* d_out, int out_size, void* d_ws, size_t ws_size,
                              hipStream_t stream) {
  const float* prop   = (const float*)d_in[0];
  const float* gt     = (const float*)d_in[1];
  const float* logits = (const float*)d_in[2];
  const float* breg   = (const float*)d_in[3];

  float* out        = (float*)d_out;
  float* out_labels = out;                                   // B*N_ALL
  float* out_regt   = out + (size_t)BATCH * N_ALL;           // B*N_ALL*4
  float* out_detb   = out_regt + (size_t)BATCH * N_ALL * 4;  // B*DETS*4
  float* out_dets   = out_detb + (size_t)BATCH * DETS * 4;   // B*DETS

  float* ws_tops   = (float*)d_ws;                            // B*PRE_NMS
  float* ws_topb   = ws_tops + (size_t)BATCH * PRE_NMS;       // B*PRE_NMS*4
  unsigned* ws_mask = (unsigned*)(ws_topb + (size_t)BATCH * PRE_NMS * 4); // B*1000*32

  hipLaunchKernelGGL(fused_select_prep_kernel,
                     dim3(SEL_BLOCKS + PREP_PER_BATCH * BATCH), dim3(1024), 0, stream,
                     prop, gt, logits, breg, out_labels, out_regt,
                     ws_tops, ws_topb);
  dim3 gridm((PRE_NMS * NWORDS + 255) / 256, BATCH);
  hipLaunchKernelGGL(mask_kernel, gridm, dim3(256), 0, stream,
                     ws_topb, ws_mask);
  hipLaunchKernelGGL(scan_kernel, dim3(BATCH), dim3(256), 0, stream,
                     ws_mask, ws_tops, ws_topb, out_detb, out_dets);
}

// Round 11
// 54.115 us; speedup vs baseline: 1.2312x; 1.0390x over previous
//
#include <hip/hip_runtime.h>
#include <math.h>

#pragma clang fp contract(off)

#define BATCH 8
#define N_PROP 8000
#define N_GT 256
#define N_ALL 8256
#define PRE_NMS 1000
#define DETS 300
#define IMG 800.0f
#define DW_CLIP 4.135166556742356f
#define NWORDS 32   // 1000 bits -> 32 u32 words
#define NBINS 8192
#define BIN_SCALE 8192.0f
#define PREP_PER_BATCH 65   // ceil(8256/128) 128-proposal blocks
#define SEL_BLOCKS 8

// Correctly-rounded f32 exp/log via double — matches the numpy reference
// transcendentals bit-for-bit (absmax 0.0 since R1). Do not touch.
__device__ __forceinline__ float exf(float x) { return (float)exp((double)x); }
__device__ __forceinline__ float lgf(float x) { return (float)log((double)x); }

__device__ __forceinline__ int score_bin(float s) {
  int b = (int)(s * BIN_SCALE);
  return (b < 0) ? 0 : (b > NBINS - 1 ? NBINS - 1 : b);
}

// bx[] LDS slot swizzle. [validated R3: SQ_LDS_BANK_CONFLICT 3.5M -> 221K]
__device__ __forceinline__ int bxp(int j) { return j ^ ((j >> 5) & 7); }

// Named scalars for the serial scan (R5-validated: arrays scratch-demote in
// complex kernels; named scalars stay in VGPRs).
#define REP32(F) F(0) F(1) F(2) F(3) F(4) F(5) F(6) F(7) F(8) F(9) F(10) \
  F(11) F(12) F(13) F(14) F(15) F(16) F(17) F(18) F(19) F(20) F(21) F(22) \
  F(23) F(24) F(25) F(26) F(27) F(28) F(29) F(30) F(31)

// R10 (R11 rebuild — fixed scope bug: rA scalars now FUNCTION-scope so they
// live across the phase-B barrier):
//  (a) SELECT single-exp softmax: m=max(x,y) makes one of e0,e1 == exp(0)
//      == 1.0 exactly; IEEE gives y-x == -(x-y) exactly; sum orders kept
//      (u+1.0f vs 1.0f+u) -> bit-identical to the two-exp form, half the
//      f64 exp work on the 8-block critical kernel.
//  (b) SCAN overlapped staging: phase-A stages rows 0..511, wave 0 scans
//      windows 0..15 (DETS-early-exit usually lands here) while waves 1-3
//      stage rows 512..999; barrier; wave 0 continues only if not done.
//      Windows >=16 read rows >=512 strictly after the phase-B barrier.

// K1: fused [select_rank (idx<8)] || [prep match+labels+encode (idx>=8)].
// [structure validated R9: absmax 0.0]
__global__ void __launch_bounds__(1024)
fused_select_prep_kernel(const float* __restrict__ prop,
                         const float* __restrict__ gt,
                         const float* __restrict__ logits,
                         const float* __restrict__ breg,
                         float* __restrict__ out_labels,
                         float* __restrict__ out_regt,
                         float* __restrict__ top_s,
                         float* __restrict__ top_b) {
  const int idx = blockIdx.x;
  const int tid = threadIdx.x;
  __shared__ __align__(16) float ssc[N_ALL];          // 33.0 KB
  __shared__ unsigned hist[NBINS];                    // 32.0 KB
  __shared__ __align__(16) float sc2[N_ALL];          // 33.0 KB
  __shared__ unsigned short idx2[N_ALL];              // 16.5 KB
  __shared__ __align__(16) float4 gsh[N_GT];          //  4.0 KB
  __shared__ int s_wt[16], s_wx[16];
  __shared__ int s_T, s_Nc;
  __shared__ __align__(16) float4 gsh4[N_GT];         //  4.0 KB (prep)
  __shared__ float s_best[128];
  __shared__ int s_bi[128];

  if (idx < SEL_BLOCKS) {
    // ================= SELECT ROLE =================
    const int b = idx;
    const int lane = tid & 63, wid = tid >> 6;

    if (tid < N_GT) gsh[tid] = ((const float4*)(gt + (size_t)b * N_GT * 4))[tid];

    // thresholded scores, SINGLE-EXP softmax (bit-exact; see header note)
    for (int k = tid; k < N_ALL; k += 1024) {
      const float2 lg = *(const float2*)(logits + ((size_t)b * N_ALL + k) * 2);
      const float d = lg.x - lg.y;
      const float u = exf((d <= 0.0f) ? d : (-d));
      const float s = (d <= 0.0f) ? (1.0f / (u + 1.0f)) : (u / (1.0f + u));
      ssc[k] = (s > 0.05f) ? s : -1.0f;
    }
    #pragma unroll
    for (int i = 0; i < NBINS / 1024; ++i) hist[tid + i * 1024] = 0u;
    __syncthreads();
    for (int k = tid; k < N_ALL; k += 1024)
      atomicAdd(&hist[score_bin(ssc[k])], 1u);
    __syncthreads();

    // thread tid owns bins [tid*8, tid*8+8)
    int local = 0;
    #pragma unroll
    for (int i = 0; i < NBINS / 1024; ++i) local += (int)hist[tid * (NBINS / 1024) + i];

    int incl = local;                       // suffix-inclusive within wave
    #pragma unroll
    for (int off = 1; off < 64; off <<= 1) {
      const int u = __shfl_down(incl, off);
      incl += (lane + off < 64) ? u : 0;
    }
    if (lane == 0) s_wt[wid] = incl;
    __syncthreads();
    if (tid < 16) {                         // suffix across the 16 waves
      const int v = s_wt[tid];
      int inc2 = v;
      #pragma unroll
      for (int off = 1; off < 16; off <<= 1) {
        const int u = __shfl_down(inc2, off);
        inc2 += (tid + off < 16) ? u : 0;
      }
      s_wx[tid] = inc2 - v;
    }
    __syncthreads();
    const int sa = (incl - local) + s_wx[wid];

    {
      int above = sa;
      const int hi = tid * (NBINS / 1024) + (NBINS / 1024) - 1;
      #pragma unroll
      for (int i = 0; i < NBINS / 1024; ++i) {
        const int bin = hi - i;
        const int c = (int)hist[bin];
        if (above < PRE_NMS && above + c >= PRE_NMS) { s_T = bin; s_Nc = above + c; }
        hist[bin] = (unsigned)above;
        above += c;
      }
    }
    __syncthreads();
    const int T = s_T;
    const int Nc = s_Nc;

    for (int k = tid; k < N_ALL; k += 1024) {
      const float v = ssc[k];
      const int bb = score_bin(v);
      if (bb >= T) {
        const int slot = (int)atomicAdd(&hist[bb], 1u);
        sc2[slot] = v;
        idx2[slot] = (unsigned short)k;
      }
    }
    __syncthreads();

    // exact rank + lazy decode of winning boxes (R7/R9-validated bit-exact)
    float* tsb = top_s + (size_t)b * PRE_NMS;
    float4* tbb = (float4*)top_b + (size_t)b * PRE_NMS;
    for (int s = tid; s < Nc; s += 1024) {
      const float my = sc2[s];
      const int myb = score_bin(my);
      const int myi = (int)idx2[s];
      int gl = s;
      while (gl > 0 && score_bin(sc2[gl - 1]) == myb) --gl;
      int rank = gl;
      for (int k2 = gl; k2 < Nc; ++k2) {
        const float v = sc2[k2];
        if (score_bin(v) != myb) break;
        if (k2 == s) continue;
        rank += (int)((v > my) | ((v == my) & ((int)idx2[k2] < myi)));
      }
      if (rank < PRE_NMS) {
        tsb[rank] = my;
        float4 pb;
        if (myi < N_PROP) pb = ((const float4*)(prop + (size_t)b * N_PROP * 4))[myi];
        else              pb = gsh[myi - N_PROP];
        const float pw = pb.z - pb.x, ph = pb.w - pb.y;
        const float pcx = pb.x + 0.5f * pw, pcy = pb.y + 0.5f * ph;
        const float4 r = *(const float4*)(breg + (((size_t)b * N_ALL + myi) * 8 + 4));
        const float dx = r.x / 10.0f, dy = r.y / 10.0f;
        const float dw = fminf(r.z / 5.0f, DW_CLIP);
        const float dh = fminf(r.w / 5.0f, DW_CLIP);
        const float cx = dx * pw + pcx, cy = dy * ph + pcy;
        const float w2 = exf(dw) * pw, h2 = exf(dh) * ph;
        float4 bb;
        bb.x = fminf(fmaxf(cx - 0.5f * w2, 0.0f), IMG);
        bb.y = fminf(fmaxf(cy - 0.5f * h2, 0.0f), IMG);
        bb.z = fminf(fmaxf(cx + 0.5f * w2, 0.0f), IMG);
        bb.w = fminf(fmaxf(cy + 0.5f * h2, 0.0f), IMG);
        tbb[rank] = bb;
      }
    }
  } else {
    // ====== PREP ROLE: IoU match + labels + encode (terminal outputs) ======
    const int pbx = idx - SEL_BLOCKS;          // [0, 520)
    const int b = pbx / PREP_PER_BATCH;
    const int blk = pbx - b * PREP_PER_BATCH;  // [0, 65)
    {
      if (tid < N_GT)
        gsh4[tid] = ((const float4*)(gt + (size_t)b * N_GT * 4))[tid];
    }
    __syncthreads();

    const int grp = tid >> 3;              // [0, 128)
    const int gl  = tid & 7;
    const int j0b = blk * 128;
    const int j = j0b + grp;               // may exceed N_ALL in last block
    const bool jv = (j < N_ALL);

    float x1, y1, x2, y2;
    if (jv && j < N_PROP) {
      const float4 p = ((const float4*)(prop + (size_t)b * N_PROP * 4))[j];
      x1 = p.x; y1 = p.y; x2 = p.z; y2 = p.w;
    } else if (jv) {
      const float4 g = gsh4[j - N_PROP];
      x1 = g.x; y1 = g.y; x2 = g.z; y2 = g.w;
    } else {
      const float4 g = gsh4[0];            // inert dummy (no stores later)
      x1 = g.x; y1 = g.y; x2 = g.z; y2 = g.w;
    }
    const float areaP = (x2 - x1) * (y2 - y1);

    float best = -1.0f; int bi = gl;
    #pragma unroll 4
    for (int t = 0; t < 32; ++t) {
      const int i = gl + (t << 3);         // in-lane ascending -> '>' keeps first
      const float4 g = gsh4[i];
      const float ga = (g.z - g.x) * (g.w - g.y);
      const float w = fmaxf(fminf(g.z, x2) - fmaxf(g.x, x1), 0.0f);
      const float h = fmaxf(fminf(g.w, y2) - fmaxf(g.y, y1), 0.0f);
      const float inter = w * h;
      const float iou = inter / (ga + areaP - inter);
      if (iou > best) { best = iou; bi = i; }
    }
    #pragma unroll
    for (int m = 1; m < 8; m <<= 1) {      // (max, min-index) == first-max
      const float ov = __shfl_xor(best, m, 64);
      const int   oi = __shfl_xor(bi,  m, 64);
      if (ov > best || (ov == best && oi < bi)) { best = ov; bi = oi; }
    }
    if (gl == 0) { s_best[grp] = best; s_bi[grp] = bi; }
    __syncthreads();

    if (tid < 128) {                       // 2 waves, one proposal each
      const int j2 = j0b + tid;
      if (j2 < N_ALL) {
        const float bst = s_best[tid];
        const int   gi  = s_bi[tid];

        float px1, py1, px2, py2;
        if (j2 < N_PROP) {
          const float4 p = ((const float4*)(prop + (size_t)b * N_PROP * 4))[j2];
          px1 = p.x; py1 = p.y; px2 = p.z; py2 = p.w;
        } else {
          const float4 g = gsh4[j2 - N_PROP];
          px1 = g.x; py1 = g.y; px2 = g.z; py2 = g.w;
        }

        out_labels[(size_t)b * N_ALL + j2] = (bst < 0.5f) ? 0.0f : 1.0f;

        const float pw = px2 - px1, ph = py2 - py1;
        const float pcx = px1 + 0.5f * pw, pcy = py1 + 0.5f * ph;
        const float4 gb = gsh4[gi];
        const float gw = gb.z - gb.x, gh = gb.w - gb.y;
        const float gcx = gb.x + 0.5f * gw, gcy = gb.y + 0.5f * gh;
        float4 rt;
        rt.x = 10.0f * (gcx - pcx) / pw;
        rt.y = 10.0f * (gcy - pcy) / ph;
        rt.z = 5.0f * lgf(gw / pw);
        rt.w = 5.0f * lgf(gh / ph);
        ((float4*)out_regt)[(size_t)b * N_ALL + j2] = rt;
      }
    }
  }
}

// K2: suppression-mask build.  [validated R2 structure + R3 bxp swizzle]
__global__ void mask_kernel(const float* __restrict__ top_b,
                            unsigned* __restrict__ ws_mask) {
  const int b = blockIdx.y;
  __shared__ __align__(16) float4 bx[PRE_NMS];
  const int tid = threadIdx.x;
  {
    const float4* gb = (const float4*)top_b + (size_t)b * PRE_NMS;
    float4 v0 = gb[tid], v1 = gb[tid + 256], v2 = gb[tid + 512];
    float4 v3 = make_float4(0.f, 0.f, 0.f, 0.f);
    const bool g3 = (tid + 768) < PRE_NMS;
    if (g3) v3 = gb[tid + 768];
    bx[bxp(tid)] = v0; bx[bxp(tid + 256)] = v1; bx[bxp(tid + 512)] = v2;
    if (g3) bx[bxp(tid + 768)] = v3;
  }
  __syncthreads();
  const int idx = blockIdx.x * blockDim.x + tid;
  if (idx >= PRE_NMS * NWORDS) return;
  const int i = idx >> 5;
  const int w = idx & 31;
  const float4 bi = bx[bxp(i)];
  const float ai = (bi.z - bi.x) * (bi.w - bi.y);
  unsigned bits = 0u;
  const int j0 = w * 32;
  #pragma unroll 8
  for (int jj = 0; jj < 32; ++jj) {
    const int j = j0 + jj;
    if (j > i && j < PRE_NMS) {
      const float4 bj = bx[bxp(j)];
      const float aj = (bj.z - bj.x) * (bj.w - bj.y);
      const float ww = fmaxf(fminf(bi.z, bj.z) - fmaxf(bi.x, bj.x), 0.0f);
      const float hh = fmaxf(fminf(bi.w, bj.w) - fmaxf(bi.y, bj.y), 0.0f);
      const float inter = ww * hh;
      const float iou = inter / (ai + aj - inter);  // NaN>0.5 false
      if (iou > 0.5f) bits |= (1u << jj);
    }
  }
  ws_mask[((size_t)b * PRE_NMS + i) * NWORDS + w] = bits;
}

// K3: serial scan + det-300 selection.  [recurrence validated R0-R9;
// DETS-early-exit validated R8]  R10/R11: two-phase staging — wave 0 scans
// windows 0..15 while waves 1-3 stage rows 512..999.  rA scalars are
// function-scope so they live across the phase-B barrier.
#define DECLA(J) unsigned rA##J = 0u;
#define LOADA(J) rA##J = smask[(base + J) * NWORDS + lw];
#define STEPJ(J) { \
  const unsigned mJ = 0u - ((sw >> J) & 1u); \
  const unsigned rwJ = (unsigned)__builtin_amdgcn_readlane((int)rA##J, win); \
  sw &= ~(rwJ & mJ); \
  sup |= (rA##J & mJ); }
#define SCAN_WIN_BODY { \
  unsigned sw = (unsigned)__builtin_amdgcn_readlane((int)keep, win); \
  if (sw) { \
    const int base = win * 32; \
    REP32(LOADA) \
    unsigned sup = 0u; \
    REP32(STEPJ) \
    keep &= ~sup; \
  } \
  int npw = n_pos - win * 32; \
  npw = (npw < 0) ? 0 : (npw > 32 ? 32 : npw); \
  const unsigned npmw = (npw >= 32) ? 0xFFFFFFFFu : ((1u << npw) - 1u); \
  { const unsigned swf = (unsigned)__builtin_amdgcn_readlane((int)keep, win); \
    c300 += __popc(swf & npmw); } \
  if (c300 >= DETS) { done = true; break; } }

__global__ void __launch_bounds__(256)
scan_kernel(const unsigned* __restrict__ ws_mask,
            const float* __restrict__ top_s,
            const float* __restrict__ top_b,
            float* __restrict__ out_detb,
            float* __restrict__ out_dets) {
  const int b = blockIdx.x;
  const int tid = threadIdx.x;
  __shared__ __align__(16) unsigned smask[PRE_NMS * NWORDS];  // 125 KiB
  __shared__ int s_npos;
  __shared__ unsigned s_flw[NWORDS];
  __shared__ int s_pref[NWORDS + 1];
  const float* ts = top_s + (size_t)b * PRE_NMS;
  const uint4* gm = (const uint4*)(ws_mask + (size_t)b * PRE_NMS * NWORDS);
  uint4* sm4 = (uint4*)smask;

  if (tid == 0) s_npos = 0;
  // phase-A stage: rows 0..511 (uint4 idx [0,4096)), 8-deep pipelined
  {
    #pragma unroll
    for (int gs = 0; gs < 2; ++gs) {
      const int k0 = gs * 2048 + tid;
      uint4 t0 = gm[k0],        t1 = gm[k0 + 256],  t2 = gm[k0 + 512];
      uint4 t3 = gm[k0 + 768],  t4 = gm[k0 + 1024], t5 = gm[k0 + 1280];
      uint4 t6 = gm[k0 + 1536], t7 = gm[k0 + 1792];
      sm4[k0] = t0;        sm4[k0 + 256] = t1;  sm4[k0 + 512] = t2;
      sm4[k0 + 768] = t3;  sm4[k0 + 1024] = t4; sm4[k0 + 1280] = t5;
      sm4[k0 + 1536] = t6; sm4[k0 + 1792] = t7;
    }
  }
  int cnt = 0;
  for (int k = tid; k < PRE_NMS; k += 256) cnt += (ts[k] > 0.0f) ? 1 : 0;
  __syncthreads();                     // phase-A visible + s_npos zeroed
  if (cnt) atomicAdd(&s_npos, cnt);
  __syncthreads();                     // n_pos final
  const int n_pos = s_npos;

  // scan state at FUNCTION scope (lives across the phase-B barrier)
  unsigned keep = 0u;
  int c300 = 0;
  bool done = false;
  const int lw = tid & 31;
  REP32(DECLA)

  if (tid < 64) {                      // wave 0: scan windows 0..15
    keep = (tid < NWORDS) ? ((tid == 31) ? 0xFFu : 0xFFFFFFFFu) : 0u;
    for (int win = 0; win < 16; ++win) SCAN_WIN_BODY
  } else {                             // waves 1-3: stage rows 512..999
    const int t2 = tid - 64;           // 0..191
    for (int k = 4096 + t2; k < PRE_NMS * NWORDS / 4; k += 192)
      sm4[k] = gm[k];
  }
  __syncthreads();                     // phase-B visible; wave 0 arrived
  if (tid < 64 && !done) {             // wave 0: continue windows 16..31
    for (int win = 16; win < 32; ++win) SCAN_WIN_BODY
  }
  __syncthreads();
  if (tid < NWORDS) {                  // wave 0 still holds keep
    const int lo = tid * 32;
    int np = n_pos - lo;
    np = (np < 0) ? 0 : (np > 32 ? 32 : np);
    const unsigned npm = (np >= 32) ? 0xFFFFFFFFu : ((1u << np) - 1u);
    s_flw[tid] = keep & npm;           // keep already 0 beyond bit 999
  }
  __syncthreads();
  if (tid == 0) {
    int s = 0;
    #pragma unroll
    for (int w = 0; w < NWORDS; ++w) { s_pref[w] = s; s += __popc(s_flw[w]); }
    s_pref[NWORDS] = s;
  }
  __syncthreads();
  const int tot = s_pref[NWORDS];

  for (int k = tid; k < PRE_NMS; k += 256) {
    const unsigned fw = s_flw[k >> 5];
    const int fbit = (int)((fw >> (k & 31)) & 1u);
    const int pos = s_pref[k >> 5] + __popc(fw & ((1u << (k & 31)) - 1u));
    int slot = -1; float sval = 0.0f;
    if (fbit) {
      if (pos < DETS) { slot = pos; sval = ts[k]; }
    } else {
      const int s2 = tot + (k - pos);
      if (s2 < DETS) { slot = s2; sval = -1.0f; }
    }
    if (slot >= 0) {
      out_dets[(size_t)b * DETS + slot] = sval;
      ((float4*)out_detb)[(size_t)b * DETS + slot] =
          ((const float4*)top_b)[(size_t)b * PRE_NMS + k];
    }
  }
}

extern "C" void kernel_launch(void* const* d_in, const int* in_sizes, int n_in,
                              void* d_out, int out_size, void* d_ws, size_t ws_size,
                              hipStream_t stream) {
  const float* prop   = (const float*)d_in[0];
  const float* gt     = (const float*)d_in[1];
  const float* logits = (const float*)d_in[2];
  const float* breg   = (const float*)d_in[3];

  float* out        = (float*)d_out;
  float* out_labels = out;                                   // B*N_ALL
  float* out_regt   = out + (size_t)BATCH * N_ALL;           // B*N_ALL*4
  float* out_detb   = out_regt + (size_t)BATCH * N_ALL * 4;  // B*DETS*4
  float* out_dets   = out_detb + (size_t)BATCH * DETS * 4;   // B*DETS

  float* ws_tops   = (float*)d_ws;                            // B*PRE_NMS
  float* ws_topb   = ws_tops + (size_t)BATCH * PRE_NMS;       // B*PRE_NMS*4
  unsigned* ws_mask = (unsigned*)(ws_topb + (size_t)BATCH * PRE_NMS * 4); // B*1000*32

  hipLaunchKernelGGL(fused_select_prep_kernel,
                     dim3(SEL_BLOCKS + PREP_PER_BATCH * BATCH), dim3(1024), 0, stream,
                     prop, gt, logits, breg, out_labels, out_regt,
                     ws_tops, ws_topb);
  dim3 gridm((PRE_NMS * NWORDS + 255) / 256, BATCH);
  hipLaunchKernelGGL(mask_kernel, gridm, dim3(256), 0, stream,
                     ws_topb, ws_mask);
  hipLaunchKernelGGL(scan_kernel, dim3(BATCH), dim3(256), 0, stream,
                     ws_mask, ws_tops, ws_topb, out_detb, out_dets);
}